// Round 3
// baseline (43.681 us; speedup 1.0000x reference)
//
#include <hip/hip_runtime.h>

// LogLinearCDE: out = softmax(W_out @ (y0 * prod_l flows[l]) + b_out)
// flows[l,h] = 1 + sum_c logsigs[l,c]*vf_A[c,h];  y0 = W_in@x0 + b_in
// Only the FINAL hidden state matters -> product over L, chunked tree-reduce.
// R3: LDS-stage the chunk's logsig rows; inner loop = LDS broadcast + FMA only.

#define LSTEPS 16384
#define HID    4096
#define CC     17
#define DD     16
#define NLAB   10
#define TPB    256
#define HP     4                       // columns per thread
#define HBLOCKS (HID/(TPB*HP))         // 4 column-blocks
#define NCHUNK 256
#define CHUNK_ROWS (LSTEPS/NCHUNK)     // 64
#define ROWPAD 20                      // 80B row stride, 16B-aligned

__global__ __launch_bounds__(TPB, 4) void partial_kernel(
    const float* __restrict__ logsigs, const float* __restrict__ vfA,
    float* __restrict__ ws_p) {
  const int hb    = blockIdx.x;
  const int chunk = blockIdx.y;
  const int h0    = hb * (TPB*HP) + threadIdx.x;

  __shared__ __align__(16) float sls[CHUNK_ROWS][ROWPAD];

  // stage chunk logsigs (64*17 = 1088 floats) with coalesced loads
  {
    const float* __restrict__ src = logsigs + (size_t)chunk * CHUNK_ROWS * CC;
    for (int e = threadIdx.x; e < CHUNK_ROWS*CC; e += TPB)
      sls[e / CC][e % CC] = src[e];
  }

  // per-thread vf_A fragment: HP columns x CC coeffs (static-indexed -> regs)
  float a[HP][CC];
  #pragma unroll
  for (int c = 0; c < CC; ++c) {
    #pragma unroll
    for (int j = 0; j < HP; ++j)
      a[j][c] = vfA[c*HID + h0 + j*TPB];
  }

  __syncthreads();

  float p[HP];
  #pragma unroll
  for (int j = 0; j < HP; ++j) p[j] = 1.0f;

  #pragma unroll 2
  for (int r = 0; r < CHUNK_ROWS; ++r) {
    // uniform-address LDS reads -> broadcast, conflict-free
    const float4 q0 = *reinterpret_cast<const float4*>(&sls[r][0]);
    const float4 q1 = *reinterpret_cast<const float4*>(&sls[r][4]);
    const float4 q2 = *reinterpret_cast<const float4*>(&sls[r][8]);
    const float4 q3 = *reinterpret_cast<const float4*>(&sls[r][12]);
    const float s16 = sls[r][16];
    const float ls[CC] = {q0.x,q0.y,q0.z,q0.w, q1.x,q1.y,q1.z,q1.w,
                          q2.x,q2.y,q2.z,q2.w, q3.x,q3.y,q3.z,q3.w, s16};
    #pragma unroll
    for (int j = 0; j < HP; ++j) {
      float f = fmaf(ls[0], a[j][0], 1.0f);
      #pragma unroll
      for (int c = 1; c < CC; ++c) f = fmaf(ls[c], a[j][c], f);
      p[j] *= f;
    }
  }
  #pragma unroll
  for (int j = 0; j < HP; ++j)
    ws_p[(size_t)chunk*HID + h0 + j*TPB] = p[j];
}

// stage A: product over cpg chunks per group; grid (HID/256, groups)
__global__ __launch_bounds__(256) void groupred_kernel(
    const float* __restrict__ ws_p, float* __restrict__ ws_g, int cpg) {
  const int h = blockIdx.x*256 + threadIdx.x;
  const int g = blockIdx.y;
  const float* __restrict__ base = ws_p + (size_t)g*cpg*HID + h;
  float p = 1.0f;
  #pragma unroll 4
  for (int k = 0; k < cpg; ++k) p *= base[(size_t)k*HID];
  ws_g[(size_t)g*HID + h] = p;
}

// stage B: product over groups, fused with y0 = W_in@x0 + b_in
__global__ __launch_bounds__(256) void finalred_kernel(
    const float* __restrict__ ws_g, const float* __restrict__ Win,
    const float* __restrict__ bin,  const float* __restrict__ x0,
    float* __restrict__ ws_y, int groups) {
  const int h = blockIdx.x*256 + threadIdx.x;
  float p = 1.0f;
  #pragma unroll 4
  for (int g = 0; g < groups; ++g) p *= ws_g[(size_t)g*HID + h];
  const float4* __restrict__ wrow = reinterpret_cast<const float4*>(Win + (size_t)h*DD);
  float y = bin[h];
  #pragma unroll
  for (int q = 0; q < DD/4; ++q) {
    float4 w = wrow[q];
    y = fmaf(w.x, x0[q*4+0], y);
    y = fmaf(w.y, x0[q*4+1], y);
    y = fmaf(w.z, x0[q*4+2], y);
    y = fmaf(w.w, x0[q*4+3], y);
  }
  ws_y[h] = y * p;
}

__global__ __launch_bounds__(256) void head_kernel(
    const float* __restrict__ ws_y, const float* __restrict__ Wout,
    const float* __restrict__ bout, float* __restrict__ out) {
  const int tid = threadIdx.x;
  float acc[NLAB];
  #pragma unroll
  for (int j = 0; j < NLAB; ++j) acc[j] = 0.0f;
  for (int h = tid; h < HID; h += 256) {
    const float y = ws_y[h];
    #pragma unroll
    for (int j = 0; j < NLAB; ++j) acc[j] = fmaf(Wout[j*HID + h], y, acc[j]);
  }
  #pragma unroll
  for (int j = 0; j < NLAB; ++j) {
    #pragma unroll
    for (int off = 32; off > 0; off >>= 1)
      acc[j] += __shfl_down(acc[j], off);
  }
  __shared__ float sm[4][NLAB];
  const int wave = tid >> 6, lane = tid & 63;
  if (lane == 0) {
    #pragma unroll
    for (int j = 0; j < NLAB; ++j) sm[wave][j] = acc[j];
  }
  __syncthreads();
  if (tid == 0) {
    float logits[NLAB];
    #pragma unroll
    for (int j = 0; j < NLAB; ++j)
      logits[j] = bout[j] + sm[0][j] + sm[1][j] + sm[2][j] + sm[3][j];
    float m = logits[0];
    #pragma unroll
    for (int j = 1; j < NLAB; ++j) m = fmaxf(m, logits[j]);
    float s = 0.0f;
    #pragma unroll
    for (int j = 0; j < NLAB; ++j) { logits[j] = __expf(logits[j] - m); s += logits[j]; }
    const float inv = 1.0f / s;
    #pragma unroll
    for (int j = 0; j < NLAB; ++j) out[j] = logits[j] * inv;
  }
}

extern "C" void kernel_launch(void* const* d_in, const int* in_sizes, int n_in,
                              void* d_out, int out_size, void* d_ws, size_t ws_size,
                              hipStream_t stream) {
  // inputs: 0=ts (unused), 1=logsigs (L,C), 2=x0 (D), 3=W_in (H,D), 4=b_in (H),
  //         5=vf_A (C,H), 6=W_out (10,H), 7=b_out (10)
  const float* logsigs = (const float*)d_in[1];
  const float* x0      = (const float*)d_in[2];
  const float* Win     = (const float*)d_in[3];
  const float* bin     = (const float*)d_in[4];
  const float* vfA     = (const float*)d_in[5];
  const float* Wout    = (const float*)d_in[6];
  const float* bout    = (const float*)d_in[7];
  float* out = (float*)d_out;

  const int groups = 16;
  const int cpg = NCHUNK / groups;

  float* ws_p = (float*)d_ws;
  float* ws_g = ws_p + (size_t)NCHUNK * HID;
  float* ws_y = ws_g + (size_t)groups * HID;

  partial_kernel<<<dim3(HBLOCKS, NCHUNK), TPB, 0, stream>>>(logsigs, vfA, ws_p);
  groupred_kernel<<<dim3(HID/256, groups), 256, 0, stream>>>(ws_p, ws_g, cpg);
  finalred_kernel<<<HID/256, 256, 0, stream>>>(ws_g, Win, bin, x0, ws_y, groups);
  head_kernel<<<1, 256, 0, stream>>>(ws_y, Wout, bout, out);
}

// Round 4
// 35.308 us; speedup vs baseline: 1.2371x; 1.2371x over previous
//
#include <hip/hip_runtime.h>
#include <hip/hip_bf16.h>
#include <stdint.h>

// LogLinearCDE: out = softmax(W_out @ (y0 * prod_l flows[l]) + b_out)
// flows[l,h] = 1 + sum_c logsigs[l,c]*vf_A[c,h];  y0 = W_in@x0 + b_in
// R4: S = logsigs@vf_A via bf16 MFMA with hi/lo fp32-split (3 MFMAs), fused
// row-product epilogue. Row-mapping of A and k-slot mapping cancel out
// (product over all 16 rows per tile); only B-col == D-col == lane&15 matters.

#define LSTEPS 16384
#define HID    4096
#define CC     17
#define DD     16
#define NLAB   10
#define NW     16          // packed u32 words per row (K padded to 32 bf16)
#define NCHUNK 256
#define CR     64          // rows per chunk
#define APAD   20          // LDS A row stride in words (80B -> 16B aligned)

typedef __attribute__((ext_vector_type(8))) short short8;
typedef __attribute__((ext_vector_type(4))) float f32x4;

static __device__ __forceinline__ unsigned short f2bf(float x) {
  __hip_bfloat16 h = __float2bfloat16(x);
  return *reinterpret_cast<unsigned short*>(&h);
}
static __device__ __forceinline__ float bf2f(unsigned short u) {
  __hip_bfloat16 h; *reinterpret_cast<unsigned short*>(&h) = u;
  return __bfloat162float(h);
}
static __device__ __forceinline__ uint32_t pack_hi(float v0, float v1) {
  return (uint32_t)f2bf(v0) | ((uint32_t)f2bf(v1) << 16);
}
static __device__ __forceinline__ uint32_t pack_lo(float v0, float v1) {
  float r0 = v0 - bf2f(f2bf(v0)), r1 = v1 - bf2f(f2bf(v1));
  return (uint32_t)f2bf(r0) | ((uint32_t)f2bf(r1) << 16);
}

// pre-pass: pack vf_A (C,H) into per-column bf16 hi/lo K-words.
// word j of column c = bf16 pair (k=2j, k=2j+1); k>=17 zero-padded.
__global__ __launch_bounds__(256) void pack_vfA_kernel(
    const float* __restrict__ vfA,
    uint32_t* __restrict__ pBh, uint32_t* __restrict__ pBl) {
  const int c = blockIdx.x*256 + threadIdx.x;        // 4096 threads
  float v[2*NW];
  #pragma unroll
  for (int k = 0; k < 2*NW; ++k) v[k] = (k < CC) ? vfA[k*HID + c] : 0.0f;
  #pragma unroll
  for (int j = 0; j < NW; ++j) {
    pBh[(size_t)c*NW + j] = pack_hi(v[2*j], v[2*j+1]);
    pBl[(size_t)c*NW + j] = pack_lo(v[2*j], v[2*j+1]);
  }
}

// partial products over 64-row chunks via MFMA
__global__ __launch_bounds__(256, 4) void partial_mfma_kernel(
    const float* __restrict__ logsigs, const uint32_t* __restrict__ pBh,
    const uint32_t* __restrict__ pBl, float* __restrict__ ws_p) {
  const int hb = blockIdx.x;        // 0..3 (1024 cols each)
  const int chunk = blockIdx.y;     // 0..255
  const int tid = threadIdx.x;

  __shared__ __align__(16) uint32_t sAh[CR][APAD], sAl[CR][APAD];

  // convert this chunk's logsig rows (64 x 17) to packed bf16 hi/lo words
  const float* __restrict__ src = logsigs + (size_t)chunk*CR*CC;
  for (int e = tid; e < CR*NW; e += 256) {
    const int r = e >> 4, j = e & (NW-1);
    const int k0 = 2*j, k1 = k0 + 1;
    const float v0 = (k0 < CC) ? src[r*CC + k0] : 0.0f;
    const float v1 = (k1 < CC) ? src[r*CC + k1] : 0.0f;
    sAh[r][j] = pack_hi(v0, v1);
    sAl[r][j] = pack_lo(v0, v1);
  }
  __syncthreads();

  const int wv = tid >> 6, lane = tid & 63;
  const int g = lane >> 4, cr = lane & 15;

  // A fragments for the 4 M-tiles (hi & lo), 16B-aligned LDS reads
  short8 Ah[4], Al[4];
  #pragma unroll
  for (int mt = 0; mt < 4; ++mt) {
    const int r = mt*16 + cr;
    Ah[mt] = *reinterpret_cast<const short8*>(&sAh[r][4*g]);
    Al[mt] = *reinterpret_cast<const short8*>(&sAl[r][4*g]);
  }

  const int cbase = hb*1024 + wv*256;
  #pragma unroll 2
  for (int nt = 0; nt < 16; ++nt) {
    const int c = cbase + nt*16 + cr;
    const short8 Bh = *reinterpret_cast<const short8*>(&pBh[(size_t)c*NW + 4*g]);
    const short8 Bl = *reinterpret_cast<const short8*>(&pBl[(size_t)c*NW + 4*g]);
    float pcol = 1.0f;
    #pragma unroll
    for (int mt = 0; mt < 4; ++mt) {
      f32x4 acc = {0.0f, 0.0f, 0.0f, 0.0f};
      acc = __builtin_amdgcn_mfma_f32_16x16x32_bf16(Ah[mt], Bh, acc, 0, 0, 0);
      acc = __builtin_amdgcn_mfma_f32_16x16x32_bf16(Ah[mt], Bl, acc, 0, 0, 0);
      acc = __builtin_amdgcn_mfma_f32_16x16x32_bf16(Al[mt], Bh, acc, 0, 0, 0);
      pcol *= (1.0f + acc[0]) * (1.0f + acc[1]) * (1.0f + acc[2]) * (1.0f + acc[3]);
    }
    // product across the 4 lane-groups -> full 64-row chunk product per column
    pcol *= __shfl_xor(pcol, 16, 64);
    pcol *= __shfl_xor(pcol, 32, 64);
    if (g == 0) ws_p[(size_t)chunk*HID + c] = pcol;
  }
}

// stage A: product over cpg chunks per group; grid (HID/256, groups)
__global__ __launch_bounds__(256) void groupred_kernel(
    const float* __restrict__ ws_p, float* __restrict__ ws_g, int cpg) {
  const int h = blockIdx.x*256 + threadIdx.x;
  const int gr = blockIdx.y;
  const float* __restrict__ base = ws_p + (size_t)gr*cpg*HID + h;
  float p = 1.0f;
  #pragma unroll 4
  for (int k = 0; k < cpg; ++k) p *= base[(size_t)k*HID];
  ws_g[(size_t)gr*HID + h] = p;
}

// stage B: product over groups, fused with y0 = W_in@x0 + b_in
__global__ __launch_bounds__(256) void finalred_kernel(
    const float* __restrict__ ws_g, const float* __restrict__ Win,
    const float* __restrict__ bin,  const float* __restrict__ x0,
    float* __restrict__ ws_y, int groups) {
  const int h = blockIdx.x*256 + threadIdx.x;
  float p = 1.0f;
  #pragma unroll 4
  for (int gr = 0; gr < groups; ++gr) p *= ws_g[(size_t)gr*HID + h];
  const float4* __restrict__ wrow = reinterpret_cast<const float4*>(Win + (size_t)h*DD);
  float y = bin[h];
  #pragma unroll
  for (int q = 0; q < DD/4; ++q) {
    float4 w = wrow[q];
    y = fmaf(w.x, x0[q*4+0], y);
    y = fmaf(w.y, x0[q*4+1], y);
    y = fmaf(w.z, x0[q*4+2], y);
    y = fmaf(w.w, x0[q*4+3], y);
  }
  ws_y[h] = y * p;
}

__global__ __launch_bounds__(256) void head_kernel(
    const float* __restrict__ ws_y, const float* __restrict__ Wout,
    const float* __restrict__ bout, float* __restrict__ out) {
  const int tid = threadIdx.x;
  float acc[NLAB];
  #pragma unroll
  for (int j = 0; j < NLAB; ++j) acc[j] = 0.0f;
  for (int h = tid; h < HID; h += 256) {
    const float y = ws_y[h];
    #pragma unroll
    for (int j = 0; j < NLAB; ++j) acc[j] = fmaf(Wout[j*HID + h], y, acc[j]);
  }
  #pragma unroll
  for (int j = 0; j < NLAB; ++j) {
    #pragma unroll
    for (int off = 32; off > 0; off >>= 1)
      acc[j] += __shfl_down(acc[j], off);
  }
  __shared__ float sm[4][NLAB];
  const int wave = tid >> 6, lane = tid & 63;
  if (lane == 0) {
    #pragma unroll
    for (int j = 0; j < NLAB; ++j) sm[wave][j] = acc[j];
  }
  __syncthreads();
  if (tid == 0) {
    float logits[NLAB];
    #pragma unroll
    for (int j = 0; j < NLAB; ++j)
      logits[j] = bout[j] + sm[0][j] + sm[1][j] + sm[2][j] + sm[3][j];
    float m = logits[0];
    #pragma unroll
    for (int j = 1; j < NLAB; ++j) m = fmaxf(m, logits[j]);
    float s = 0.0f;
    #pragma unroll
    for (int j = 0; j < NLAB; ++j) { logits[j] = __expf(logits[j] - m); s += logits[j]; }
    const float inv = 1.0f / s;
    #pragma unroll
    for (int j = 0; j < NLAB; ++j) out[j] = logits[j] * inv;
  }
}

extern "C" void kernel_launch(void* const* d_in, const int* in_sizes, int n_in,
                              void* d_out, int out_size, void* d_ws, size_t ws_size,
                              hipStream_t stream) {
  // inputs: 0=ts (unused), 1=logsigs (L,C), 2=x0 (D), 3=W_in (H,D), 4=b_in (H),
  //         5=vf_A (C,H), 6=W_out (10,H), 7=b_out (10)
  const float* logsigs = (const float*)d_in[1];
  const float* x0      = (const float*)d_in[2];
  const float* Win     = (const float*)d_in[3];
  const float* bin     = (const float*)d_in[4];
  const float* vfA     = (const float*)d_in[5];
  const float* Wout    = (const float*)d_in[6];
  const float* bout    = (const float*)d_in[7];
  float* out = (float*)d_out;

  const int groups = 16;
  const int cpg = NCHUNK / groups;

  // workspace layout (all 16B-aligned)
  float*    ws_p = (float*)d_ws;                                   // 256*4096 f32 = 4 MB
  float*    ws_g = ws_p + (size_t)NCHUNK * HID;                    // 16*4096 f32
  float*    ws_y = ws_g + (size_t)groups * HID;                    // 4096 f32
  uint32_t* pBh  = (uint32_t*)(ws_y + HID);                        // 4096*16 u32
  uint32_t* pBl  = pBh + (size_t)HID * NW;                         // 4096*16 u32

  pack_vfA_kernel<<<HID/256, 256, 0, stream>>>(vfA, pBh, pBl);
  partial_mfma_kernel<<<dim3(4, NCHUNK), 256, 0, stream>>>(logsigs, pBh, pBl, ws_p);
  groupred_kernel<<<dim3(HID/256, groups), 256, 0, stream>>>(ws_p, ws_g, cpg);
  finalred_kernel<<<HID/256, 256, 0, stream>>>(ws_g, Win, bin, x0, ws_y, groups);
  head_kernel<<<1, 256, 0, stream>>>(ws_y, Wout, bout, out);
}